// Round 11
// baseline (80.664 us; speedup 1.0000x reference)
//
#include <hip/hip_runtime.h>
#include <hip/hip_bf16.h>

#define HW   8192
#define W0   128
#define H0   64
#define CDIM 256

__device__ __forceinline__ int dot4(unsigned int a, unsigned int b, int acc) {
#if __has_builtin(__builtin_amdgcn_sdot4)
    return __builtin_amdgcn_sdot4((int)a, (int)b, acc, false);
#else
    int r = acc;
    #pragma unroll
    for (int k = 0; k < 4; ++k) {
        r += (int)(signed char)(a >> (8 * k)) * (int)(signed char)(b >> (8 * k));
    }
    return r;
#endif
}

// ---------- K1: transpose+quantize fmap1 -> q1[8192][256] int8, s1[8192] ----------
// s1 folds the 1/16 correlation scale.
__global__ __launch_bounds__(256) void k_q_f1(const float* __restrict__ in,
                                              signed char* __restrict__ q1,
                                              float* __restrict__ s1) {
    __shared__ float lds[32][257];
    __shared__ float sInv[32];
    __shared__ float sSc[32];
    const int m0 = blockIdx.x * 32;
    const int tc = threadIdx.x & 31;
    const int tr = threadIdx.x >> 5;
    #pragma unroll 4
    for (int r = 0; r < 32; ++r) {
        const int c = r * 8 + tr;
        lds[tc][c] = in[(size_t)c * HW + m0 + tc];
    }
    __syncthreads();
    // per-row absmax: 8 threads per row
    const int row = threadIdx.x >> 3, t8 = threadIdx.x & 7;
    float am = 0.f;
    #pragma unroll 8
    for (int k = 0; k < 32; ++k) am = fmaxf(am, fabsf(lds[row][t8 * 32 + k]));
    am = fmaxf(am, __shfl_xor(am, 1));
    am = fmaxf(am, __shfl_xor(am, 2));
    am = fmaxf(am, __shfl_xor(am, 4));
    if (t8 == 0) {
        sInv[row] = am > 0.f ? 127.f / am : 0.f;
        sSc[row]  = (am / 127.f) * 0.0625f;
    }
    __syncthreads();
    const int c = threadIdx.x;
    #pragma unroll 4
    for (int ml = 0; ml < 32; ++ml) {
        q1[(size_t)(m0 + ml) * CDIM + c] =
            (signed char)__float2int_rn(lds[ml][c] * sInv[ml]);
    }
    if (threadIdx.x < 32) s1[m0 + threadIdx.x] = sSc[threadIdx.x];
}

// ---------- K2: transpose fmap2 [256][8192] -> pyramid level0 HWC f16 ----------
__global__ __launch_bounds__(256) void k_transpose_f2(const float* __restrict__ in,
                                                      _Float16* __restrict__ outT) {
    __shared__ float lds[32][257];
    const int m0 = blockIdx.x * 32;
    const int tc = threadIdx.x & 31;
    const int tr = threadIdx.x >> 5;
    #pragma unroll 4
    for (int r = 0; r < 32; ++r) {
        const int c = r * 8 + tr;
        lds[tc][c] = in[(size_t)c * HW + m0 + tc];
    }
    __syncthreads();
    const int c = threadIdx.x;
    #pragma unroll 4
    for (int ml = 0; ml < 32; ++ml) {
        outT[(size_t)(m0 + ml) * CDIM + c] = (_Float16)lds[ml][c];
    }
}

// ---------- K3: 2x2 avg pool, HWC f16 -> HWC f16 ----------
__global__ __launch_bounds__(256) void k_pool(const _Float16* __restrict__ in,
                                              _Float16* __restrict__ out,
                                              int Wout, int Win) {
    const int c = threadIdx.x;
    const int b = blockIdx.x;
    const int X = b % Wout;
    const int Y = b / Wout;
    const size_t base = ((size_t)(2 * Y) * Win + 2 * X) * CDIM + c;
    const size_t rows = (size_t)Win * CDIM;
    float s = (float)in[base] + (float)in[base + CDIM] +
              (float)in[base + rows] + (float)in[base + rows + CDIM];
    out[(size_t)b * CDIM + c] = (_Float16)(s * 0.25f);
}

// ---------- K3b: per-texel int8 quantization of the pyramid ----------
__global__ __launch_bounds__(256) void k_quant(const _Float16* __restrict__ pf,
                                               unsigned int* __restrict__ pq,
                                               float* __restrict__ s2, int ntex) {
    const int t = blockIdx.x * 4 + (threadIdx.x >> 6);
    if (t >= ntex) return;
    const int lane = threadIdx.x & 63;
    const _Float16* p = pf + (size_t)t * CDIM + lane * 4;
    const float a0 = (float)p[0], a1 = (float)p[1], a2 = (float)p[2], a3 = (float)p[3];
    float am = fmaxf(fmaxf(fabsf(a0), fabsf(a1)), fmaxf(fabsf(a2), fabsf(a3)));
    #pragma unroll
    for (int d = 1; d < 64; d <<= 1) am = fmaxf(am, __shfl_xor(am, d));
    const float inv = am > 0.f ? 127.f / am : 0.f;
    const unsigned int q0 = (unsigned int)__float2int_rn(a0 * inv) & 255u;
    const unsigned int q1 = (unsigned int)__float2int_rn(a1 * inv) & 255u;
    const unsigned int q2 = (unsigned int)__float2int_rn(a2 * inv) & 255u;
    const unsigned int q3 = (unsigned int)__float2int_rn(a3 * inv) & 255u;
    pq[(size_t)t * 64 + lane] = q0 | (q1 << 8) | (q2 << 16) | (q3 << 24);
    if (lane == 0) s2[t] = am / 127.f;
}

// ---------- K4: fused correlation sampling, int8 dot4, LEVEL-SYNCED ----------
// 512 blocks x 1024 threads (16 waves). Wave wv = pixel m0+wv.
// All 16 waves process the SAME pyramid level concurrently (barrier per
// level) so the 10-16x inter-pixel window overlap becomes L1-temporal
// locality instead of L2 re-reads.
__global__ __launch_bounds__(1024, 4) void k_sample(const signed char* __restrict__ q1,
                                                    const float* __restrict__ s1,
                                                    const unsigned char* __restrict__ pyrQ,
                                                    const float* __restrict__ s2,
                                                    const float* __restrict__ coords,
                                                    float* __restrict__ out) {
    const int tid  = threadIdx.x;
    const int wv   = tid >> 6;
    const int lane = tid & 63;
    const int grp  = lane >> 3;
    const int sub  = lane & 7;
    const int m0   = blockIdx.x * 16;
    const int m    = m0 + wv;

    __shared__ float sG[16][4][105];
    __shared__ float sF[16][4][2];
    __shared__ float sS[16];

    if (tid < 16) sS[tid] = s1[m0 + tid];

    // f1 fragment: 32 channels (32 B int8) per lane
    const uint4* f1p = reinterpret_cast<const uint4*>(q1 + (size_t)m * CDIM + sub * 32);
    const uint4 Fa = f1p[0], Fb = f1p[1];

    const float cx = coords[m];
    const float cy = coords[HW + m];

    #pragma unroll
    for (int w = 0; w < 4; ++w) {
        const int Wl = W0 >> w;
        const int Hl = H0 >> w;
        const int texoff = (w == 0) ? 0 : (w == 1) ? 8192 : (w == 2) ? 10240 : 10752;
        const unsigned char* lvl = pyrQ + ((size_t)texoff << 8);
        const float* s2l = s2 + texoff;
        const float scale = 1.0f / (float)(1 << w);

        const float xs = cx * scale;
        const float ys = cy * scale;
        const float X0f = floorf(xs), Y0f = floorf(ys);
        const int X0 = (int)X0f, Y0 = (int)Y0f;
        if (lane == 0) { sF[wv][w][0] = xs - X0f; sF[wv][w][1] = ys - Y0f; }

        for (int it = 0; it < 13; ++it) {
            const int p = it * 8 + grp;           // grid point 0..103 (mask >=100)
            const int j = (p * 205) >> 11;        // p / 10
            const int i = p - j * 10;
            const int gy = Y0 - 4 + j;
            const int gx = X0 - 4 + i;
            const bool ok = (p < 100) && ((unsigned)gy < (unsigned)Hl) &&
                            ((unsigned)gx < (unsigned)Wl);
            int acc = 0;
            if (ok) {
                const uint4* q = reinterpret_cast<const uint4*>(
                    lvl + (((size_t)(gy * Wl + gx)) << 8) + sub * 32);
                const uint4 A = q[0], B = q[1];
                acc = dot4(A.x, Fa.x, acc); acc = dot4(A.y, Fa.y, acc);
                acc = dot4(A.z, Fa.z, acc); acc = dot4(A.w, Fa.w, acc);
                acc = dot4(B.x, Fb.x, acc); acc = dot4(B.y, Fb.y, acc);
                acc = dot4(B.z, Fb.z, acc); acc = dot4(B.w, Fb.w, acc);
            }
            acc += __shfl_xor(acc, 1);
            acc += __shfl_xor(acc, 2);
            acc += __shfl_xor(acc, 4);
            float gv = 0.f;
            if (ok) gv = (float)acc * s2l[gy * Wl + gx];
            if (sub == 0 && p < 100) sG[wv][w][p] = gv;
        }
        __syncthreads();   // keep all 16 waves on the same level: L1 temporal locality
    }

    const int cpx = tid & 15;
    const float s1v = sS[cpx];
    for (int o = tid >> 4; o < 324; o += 64) {
        const int lev = (o * 811) >> 16;          // o / 81
        const int k   = o - lev * 81;
        const int a   = (k * 57) >> 9;            // k / 9  (x-offset index)
        const int bb  = k - a * 9;                // k % 9  (y-offset index)
        const float fx = sF[cpx][lev][0], fy = sF[cpx][lev][1];
        const float wx0 = 1.0f - fx, wy0 = 1.0f - fy;
        const float* G = sG[cpx][lev];
        const float v = wy0 * (wx0 * G[bb * 10 + a]       + fx * G[bb * 10 + a + 1])
                      + fy  * (wx0 * G[(bb + 1) * 10 + a] + fx * G[(bb + 1) * 10 + a + 1]);
        out[(size_t)o * HW + m0 + cpx] = v * s1v;
    }
}

extern "C" void kernel_launch(void* const* d_in, const int* in_sizes, int n_in,
                              void* d_out, int out_size, void* d_ws, size_t ws_size,
                              hipStream_t stream) {
    const float* fmap1  = (const float*)d_in[0];
    const float* fmap2  = (const float*)d_in[1];
    const float* coords = (const float*)d_in[2];
    float* out = (float*)d_out;

    char* ws = (char*)d_ws;
    signed char* q1  = (signed char*)ws;                    // 2,097,152
    float* s1        = (float*)(ws + 2097152);              // 32,768
    float* s2        = (float*)(ws + 2129920);              // 43,520
    unsigned char* pyrQ = (unsigned char*)(ws + 2176000);   // 2,785,280
    _Float16* pyrF   = (_Float16*)(ws + 4961280);           // 5,570,560
    _Float16* p0 = pyrF;                // 64x128x256
    _Float16* p1 = pyrF + 2097152;      // 32x64x256
    _Float16* p2 = pyrF + 2621440;      // 16x32x256
    _Float16* p3 = pyrF + 2752512;      //  8x16x256

    k_transpose_f2<<<HW / 32, 256, 0, stream>>>(fmap2, p0);
    k_pool<<<32 * 64, 256, 0, stream>>>(p0, p1, 64, 128);
    k_pool<<<16 * 32, 256, 0, stream>>>(p1, p2, 32, 64);
    k_pool<<<8 * 16, 256, 0, stream>>>(p2, p3, 16, 32);
    k_quant<<<(10880 + 3) / 4, 256, 0, stream>>>(pyrF, (unsigned int*)pyrQ, s2, 10880);
    k_q_f1<<<HW / 32, 256, 0, stream>>>(fmap1, q1, s1);
    k_sample<<<HW / 16, 1024, 0, stream>>>(q1, s1, pyrQ, s2, coords, out);
}

// Round 14
// 62.982 us; speedup vs baseline: 1.2807x; 1.2807x over previous
//
#include <hip/hip_runtime.h>
#include <hip/hip_bf16.h>

#define HW   8192
#define W0   128
#define H0   64
#define CDIM 256

typedef int int4v __attribute__((ext_vector_type(4)));

__device__ __forceinline__ int4v mfma_i8_16x16x64(int4v a, int4v b, int4v c) {
    asm volatile("v_mfma_i32_16x16x64_i8 %0, %1, %2, %0"
                 : "+v"(c) : "v"(a), "v"(b));
    return c;
}

// ---------- K1: transpose+quantize fmap1 -> q1[8192][256] int8, s1[8192] ----------
__global__ __launch_bounds__(256) void k_q_f1(const float* __restrict__ in,
                                              signed char* __restrict__ q1,
                                              float* __restrict__ s1) {
    __shared__ float lds[32][257];
    __shared__ float sInv[32];
    __shared__ float sSc[32];
    const int m0 = blockIdx.x * 32;
    const int tc = threadIdx.x & 31;
    const int tr = threadIdx.x >> 5;
    #pragma unroll 4
    for (int r = 0; r < 32; ++r) {
        const int c = r * 8 + tr;
        lds[tc][c] = in[(size_t)c * HW + m0 + tc];
    }
    __syncthreads();
    const int row = threadIdx.x >> 3, t8 = threadIdx.x & 7;
    float am = 0.f;
    #pragma unroll 8
    for (int k = 0; k < 32; ++k) am = fmaxf(am, fabsf(lds[row][t8 * 32 + k]));
    am = fmaxf(am, __shfl_xor(am, 1));
    am = fmaxf(am, __shfl_xor(am, 2));
    am = fmaxf(am, __shfl_xor(am, 4));
    if (t8 == 0) {
        sInv[row] = am > 0.f ? 127.f / am : 0.f;
        sSc[row]  = (am / 127.f) * 0.0625f;
    }
    __syncthreads();
    const int c = threadIdx.x;
    #pragma unroll 4
    for (int ml = 0; ml < 32; ++ml) {
        q1[(size_t)(m0 + ml) * CDIM + c] =
            (signed char)__float2int_rn(lds[ml][c] * sInv[ml]);
    }
    if (threadIdx.x < 32) s1[m0 + threadIdx.x] = sSc[threadIdx.x];
}

// ---------- K2: transpose fmap2 [256][8192] -> pyramid level0 HWC f16 ----------
__global__ __launch_bounds__(256) void k_transpose_f2(const float* __restrict__ in,
                                                      _Float16* __restrict__ outT) {
    __shared__ float lds[32][257];
    const int m0 = blockIdx.x * 32;
    const int tc = threadIdx.x & 31;
    const int tr = threadIdx.x >> 5;
    #pragma unroll 4
    for (int r = 0; r < 32; ++r) {
        const int c = r * 8 + tr;
        lds[tc][c] = in[(size_t)c * HW + m0 + tc];
    }
    __syncthreads();
    const int c = threadIdx.x;
    #pragma unroll 4
    for (int ml = 0; ml < 32; ++ml) {
        outT[(size_t)(m0 + ml) * CDIM + c] = (_Float16)lds[ml][c];
    }
}

// ---------- K3: 2x2 avg pool, HWC f16 -> HWC f16 ----------
__global__ __launch_bounds__(256) void k_pool(const _Float16* __restrict__ in,
                                              _Float16* __restrict__ out,
                                              int Wout, int Win) {
    const int c = threadIdx.x;
    const int b = blockIdx.x;
    const int X = b % Wout;
    const int Y = b / Wout;
    const size_t base = ((size_t)(2 * Y) * Win + 2 * X) * CDIM + c;
    const size_t rows = (size_t)Win * CDIM;
    float s = (float)in[base] + (float)in[base + CDIM] +
              (float)in[base + rows] + (float)in[base + rows + CDIM];
    out[(size_t)b * CDIM + c] = (_Float16)(s * 0.25f);
}

// ---------- K3b: per-texel int8 quantization of the pyramid ----------
__global__ __launch_bounds__(256) void k_quant(const _Float16* __restrict__ pf,
                                               unsigned int* __restrict__ pq,
                                               float* __restrict__ s2, int ntex) {
    const int t = blockIdx.x * 4 + (threadIdx.x >> 6);
    if (t >= ntex) return;
    const int lane = threadIdx.x & 63;
    const _Float16* p = pf + (size_t)t * CDIM + lane * 4;
    const float a0 = (float)p[0], a1 = (float)p[1], a2 = (float)p[2], a3 = (float)p[3];
    float am = fmaxf(fmaxf(fabsf(a0), fabsf(a1)), fmaxf(fabsf(a2), fabsf(a3)));
    #pragma unroll
    for (int d = 1; d < 64; d <<= 1) am = fmaxf(am, __shfl_xor(am, d));
    const float inv = am > 0.f ? 127.f / am : 0.f;
    const unsigned int q0 = (unsigned int)__float2int_rn(a0 * inv) & 255u;
    const unsigned int q1 = (unsigned int)__float2int_rn(a1 * inv) & 255u;
    const unsigned int q2 = (unsigned int)__float2int_rn(a2 * inv) & 255u;
    const unsigned int q3 = (unsigned int)__float2int_rn(a3 * inv) & 255u;
    pq[(size_t)t * 64 + lane] = q0 | (q1 << 8) | (q2 << 16) | (q3 << 24);
    if (lane == 0) s2[t] = am / 127.f;
}

// ---------- K4 (MFMA via inline asm): block-bbox GEMM + scatter ----------
// 512 blocks x 1024 threads (16 waves), 16 pixels/block.
// Per level: block-uniform bbox of the 16 windows; waves grab (row, 16-texel
// chunk) items; each item = [16px x 256ch] x [256ch x 16tex] via 4x
// v_mfma_i32_16x16x64_i8. Each texel crosses L2 once per BLOCK (~2.6x fewer
// L2 bytes than per-pixel gather). D (col=lane&15=texel,
// row=(lane>>4)*4+reg=pixel) scaled by s2, scattered into sG w/ bounds checks.
__global__ __launch_bounds__(1024, 4) void k_sample_mfma(
        const signed char* __restrict__ q1, const float* __restrict__ s1,
        const unsigned char* __restrict__ pyrQ, const float* __restrict__ s2,
        const float* __restrict__ coords, float* __restrict__ out) {
    const int tid  = threadIdx.x;
    const int wv   = tid >> 6;
    const int lane = tid & 63;
    const int m0   = blockIdx.x * 16;

    __shared__ float sG[16][4][105];
    __shared__ float sF[16][4][2];
    __shared__ float sS[16];
    __shared__ int   sX0[4][16];
    __shared__ int   sY0[4][16];

    {
        float* gz = &sG[0][0][0];
        for (int k = tid; k < 16 * 4 * 105; k += 1024) gz[k] = 0.f;
    }
    if (tid < 16) {
        sS[tid] = s1[m0 + tid];
        const float cx = coords[m0 + tid];
        const float cy = coords[HW + m0 + tid];
        #pragma unroll
        for (int w = 0; w < 4; ++w) {
            const float scale = 1.0f / (float)(1 << w);
            const float xs = cx * scale, ys = cy * scale;
            const float X0f = floorf(xs), Y0f = floorf(ys);
            sX0[w][tid] = (int)X0f;
            sY0[w][tid] = (int)Y0f;
            sF[tid][w][0] = xs - X0f;
            sF[tid][w][1] = ys - Y0f;
        }
    }
    __syncthreads();

    // A fragments: lane holds pixel (lane&15), channels (lane>>4)*16 + 64*kk
    const signed char* ap = q1 + (size_t)(m0 + (lane & 15)) * CDIM + ((lane >> 4) << 4);
    const int4v A0 = *reinterpret_cast<const int4v*>(ap);
    const int4v A1 = *reinterpret_cast<const int4v*>(ap + 64);
    const int4v A2 = *reinterpret_cast<const int4v*>(ap + 128);
    const int4v A3 = *reinterpret_cast<const int4v*>(ap + 192);

    #pragma unroll
    for (int w = 0; w < 4; ++w) {
        const int Wl = W0 >> w;
        const int Hl = H0 >> w;
        const int texoff = (w == 0) ? 0 : (w == 1) ? 8192 : (w == 2) ? 10240 : 10752;
        const signed char* lvl = (const signed char*)pyrQ + ((size_t)texoff << 8);
        const float* s2l = s2 + texoff;

        int minX = 1 << 30, maxX = -(1 << 30), minY = 1 << 30, maxY = -(1 << 30);
        #pragma unroll
        for (int p = 0; p < 16; ++p) {
            const int x0 = sX0[w][p], y0 = sY0[w][p];
            minX = min(minX, x0); maxX = max(maxX, x0);
            minY = min(minY, y0); maxY = max(maxY, y0);
        }
        const int xlo = max(minX - 4, 0), xhi = min(maxX + 5, Wl - 1);
        const int ylo = max(minY - 4, 0), yhi = min(maxY + 5, Hl - 1);
        if (xlo > xhi || ylo > yhi) continue;
        const int span  = xhi - xlo + 1;
        const int cpr   = (span + 15) >> 4;
        const int items = (yhi - ylo + 1) * cpr;

        for (int it = wv; it < items; it += 16) {
            const int rowi = it / cpr;
            const int gy   = ylo + rowi;
            const int t0   = xlo + (it - rowi * cpr) * 16;
            const int gxl  = t0 + (lane & 15);
            const int gxc  = min(gxl, xhi);
            const signed char* bp = lvl + (((size_t)(gy * Wl + gxc)) << 8) + ((lane >> 4) << 4);
            int4v acc = {0, 0, 0, 0};
            acc = mfma_i8_16x16x64(A0, *reinterpret_cast<const int4v*>(bp),       acc);
            acc = mfma_i8_16x16x64(A1, *reinterpret_cast<const int4v*>(bp + 64),  acc);
            acc = mfma_i8_16x16x64(A2, *reinterpret_cast<const int4v*>(bp + 128), acc);
            acc = mfma_i8_16x16x64(A3, *reinterpret_cast<const int4v*>(bp + 192), acc);
            const float s2v = s2l[gy * Wl + gxc];
            const bool xok = (gxl <= xhi);
            #pragma unroll
            for (int r = 0; r < 4; ++r) {
                const int px = ((lane >> 4) << 2) + r;
                const int j = gy - sY0[w][px] + 4;
                const int i = gxl - sX0[w][px] + 4;
                if (xok && (unsigned)j < 10u && (unsigned)i < 10u)
                    sG[px][w][j * 10 + i] = (float)acc[r] * s2v;
            }
        }
    }
    __syncthreads();

    const int cpx = tid & 15;
    const float s1v = sS[cpx];
    for (int o = tid >> 4; o < 324; o += 64) {
        const int lev = (o * 811) >> 16;
        const int k   = o - lev * 81;
        const int a   = (k * 57) >> 9;
        const int bb  = k - a * 9;
        const float fx = sF[cpx][lev][0], fy = sF[cpx][lev][1];
        const float wx0 = 1.0f - fx, wy0 = 1.0f - fy;
        const float* G = sG[cpx][lev];
        const float v = wy0 * (wx0 * G[bb * 10 + a]       + fx * G[bb * 10 + a + 1])
                      + fy  * (wx0 * G[(bb + 1) * 10 + a] + fx * G[(bb + 1) * 10 + a + 1]);
        out[(size_t)o * HW + m0 + cpx] = v * s1v;
    }
}

extern "C" void kernel_launch(void* const* d_in, const int* in_sizes, int n_in,
                              void* d_out, int out_size, void* d_ws, size_t ws_size,
                              hipStream_t stream) {
    const float* fmap1  = (const float*)d_in[0];
    const float* fmap2  = (const float*)d_in[1];
    const float* coords = (const float*)d_in[2];
    float* out = (float*)d_out;

    char* ws = (char*)d_ws;
    signed char* q1  = (signed char*)ws;                    // 2,097,152
    float* s1        = (float*)(ws + 2097152);              // 32,768
    float* s2        = (float*)(ws + 2129920);              // 43,520
    unsigned char* pyrQ = (unsigned char*)(ws + 2176000);   // 2,785,280
    _Float16* pyrF   = (_Float16*)(ws + 4961280);           // 5,570,560
    _Float16* p0 = pyrF;                // 64x128x256
    _Float16* p1 = pyrF + 2097152;      // 32x64x256
    _Float16* p2 = pyrF + 2621440;      // 16x32x256
    _Float16* p3 = pyrF + 2752512;      //  8x16x256

    k_transpose_f2<<<HW / 32, 256, 0, stream>>>(fmap2, p0);
    k_pool<<<32 * 64, 256, 0, stream>>>(p0, p1, 64, 128);
    k_pool<<<16 * 32, 256, 0, stream>>>(p1, p2, 32, 64);
    k_pool<<<8 * 16, 256, 0, stream>>>(p2, p3, 16, 32);
    k_quant<<<(10880 + 3) / 4, 256, 0, stream>>>(pyrF, (unsigned int*)pyrQ, s2, 10880);
    k_q_f1<<<HW / 32, 256, 0, stream>>>(fmap1, q1, s1);
    k_sample_mfma<<<HW / 16, 1024, 0, stream>>>(q1, s1, pyrQ, s2, coords, out);
}